// Round 5
// baseline (90.088 us; speedup 1.0000x reference)
//
#include <hip/hip_runtime.h>

typedef __attribute__((ext_vector_type(8))) short bf16x8;
typedef __attribute__((ext_vector_type(4))) float f32x4;

#define EPSV 1e-5f
// (1/TEMP) * log2(e),  TEMP = 0.5  -> exp2-domain scale
#define SCALE 2.885390081777927f

// NOTE: must be the builtin — raw inline-asm v_exp_f32 lacks the TRANS-pipe
// hazard nop (asm is opaque to the hazard recognizer) and returns garbage.
__device__ __forceinline__ float fast_exp2(float x) { return __builtin_amdgcn_exp2f(x); }

__device__ __forceinline__ ushort f32_to_bf16(float f) {
  union { float f; unsigned u; } cv; cv.f = f;
  unsigned u = cv.u;
  u += 0x7FFFu + ((u >> 16) & 1u);   // round-to-nearest-even
  return (ushort)(u >> 16);
}

// ---------------------------------------------------------------------------
// Fused prep kernel, grid = 512 + 512 + 64 = 1088 blocks, 256 threads.
//  [0,512):   pack anchors  [B,C,H,W] f32 -> Apk[p][n][c] bf16 (coalesced via
//             LDS transpose) + pos-pair dot posDot[p*64+n] (f32)
//  [512,1024): per-patch label mean -> flags
//  [1024,1088): bank repack [L,C,8,8] f32 -> [2048][256] bf16, pre-scaled
// ---------------------------------------------------------------------------
__global__ __launch_bounds__(256) void cpl_prep(
    const float* __restrict__ mainO, const float* __restrict__ emaO,
    const float* __restrict__ label, const float* __restrict__ negB,
    const float* __restrict__ posB,
    ushort* __restrict__ Apk, float* __restrict__ posDot,
    int* __restrict__ flags, ushort* __restrict__ bankN, ushort* __restrict__ bankP)
{
  __shared__ ushort shU[64 * 256];   // 32 KiB
  __shared__ float  shF[4][64];
  const int bid = blockIdx.x;
  const int t = threadIdx.x;

  if (bid < 512) {
    // ---- anchor pack + pos dot: block = (b, y) ----
    const int b = bid >> 6, y = bid & 63;
    const int cg = t >> 4;            // c-offset 0..15
    const int x4 = t & 15;            // float4 index along W
    const float* mB = mainO + (((size_t)b * 256 + cg) * 64 + y) * 64 + x4 * 4;
    const float* eB = emaO  + (((size_t)b * 256 + cg) * 64 + y) * 64 + x4 * 4;
    float4 acc4 = make_float4(0.f, 0.f, 0.f, 0.f);
#pragma unroll
    for (int pass = 0; pass < 16; ++pass) {
      const int c = pass * 16 + cg;
      const float4 mv = *(const float4*)(mB + (size_t)pass * 16 * 4096);
      const float4 ev = *(const float4*)(eB + (size_t)pass * 16 * 4096);
      acc4.x += mv.x * ev.x; acc4.y += mv.y * ev.y;
      acc4.z += mv.z * ev.z; acc4.w += mv.w * ev.w;
      const float vals[4] = {mv.x, mv.y, mv.z, mv.w};
#pragma unroll
      for (int j = 0; j < 4; ++j) {
        const int x = x4 * 4 + j;
        shU[x * 256 + (c ^ ((x & 7) << 3))] = f32_to_bf16(vals[j]);
      }
    }
    // reduce pos partials over c-groups (cg bit0 = lane bit4, bit1 = lane bit5)
    acc4.x += __shfl_xor(acc4.x, 16, 64); acc4.y += __shfl_xor(acc4.y, 16, 64);
    acc4.z += __shfl_xor(acc4.z, 16, 64); acc4.w += __shfl_xor(acc4.w, 16, 64);
    acc4.x += __shfl_xor(acc4.x, 32, 64); acc4.y += __shfl_xor(acc4.y, 32, 64);
    acc4.z += __shfl_xor(acc4.z, 32, 64); acc4.w += __shfl_xor(acc4.w, 32, 64);
    if ((t & 63) < 16) *(float4*)&shF[t >> 6][(t & 15) * 4] = acc4;
    __syncthreads();
    // write packed anchors (coalesced b128)
#pragma unroll
    for (int it = 0; it < 8; ++it) {
      const int lin = it * 256 + t;          // 0..2047
      const int x = lin >> 5, c8 = lin & 31;
      const uint4 v = *(const uint4*)&shU[x * 256 + ((c8 * 8) ^ ((x & 7) << 3))];
      const int p = b * 64 + ((y >> 3) << 3) + (x >> 3);
      const int n = ((y & 7) << 3) + (x & 7);
      *(uint4*)&Apk[((size_t)p * 64 + n) * 256 + c8 * 8] = v;
    }
    if (t < 64) {
      const float pv = shF[0][t] + shF[1][t] + shF[2][t] + shF[3][t];
      const int p = b * 64 + ((y >> 3) << 3) + (t >> 3);
      const int n = ((y & 7) << 3) + (t & 7);
      posDot[p * 64 + n] = pv;
    }
  } else if (bid < 1024) {
    // ---- label mean -> flag ----
    const int p = bid - 512;
    const int b = p >> 6, pj = (p >> 3) & 7, pk = p & 7;
    const size_t base = ((size_t)b * 256 + pj * 32) * 256 + pk * 32;
    float s = 0.f;
#pragma unroll
    for (int i = 0; i < 4; ++i) {
      const int e = t * 4 + i;               // 0..1023, r=e>>5, cc=e&31
      s += label[base + (size_t)(e >> 5) * 256 + (e & 31)];
    }
#pragma unroll
    for (int d = 1; d < 64; d <<= 1) s += __shfl_xor(s, d, 64);
    if ((t & 63) == 0) shF[0][t >> 6] = s;
    __syncthreads();
    if (t == 0)
      flags[p] = ((shF[0][0] + shF[0][1] + shF[0][2] + shF[0][3]) * (1.f / 1024.f) < 0.1f) ? 1 : 0;
  } else {
    // ---- bank repack (pre-scaled by SCALE) ----
    const int bb = bid - 1024;
    const float* src = (bb < 32 ? negB : posB) + (size_t)(bb & 31) * 16384;
    ushort* dst = (bb < 32 ? bankN : bankP) + (size_t)(bb & 31) * 64 * 256;
#pragma unroll 8
    for (int it = 0; it < 64; ++it) {
      const int lin = it * 256 + t;          // [c][posi] linear, coalesced read
      const int c = lin >> 6, posi = lin & 63;
      shU[(posi * 256 + c) ^ ((posi & 31) << 1)] = f32_to_bf16(src[lin] * SCALE);
    }
    __syncthreads();
    unsigned* dst32 = (unsigned*)dst;
#pragma unroll 8
    for (int it = 0; it < 32; ++it) {
      const int lin = it * 256 + t;          // uint index: 128 uints per row
      const int posi = lin >> 7, c = (lin & 127) << 1;
      const int idx = (posi * 256 + c) ^ ((posi & 31) << 1);
      dst32[lin] = *(const unsigned*)&shU[idx];
    }
  }
}

// ---------------------------------------------------------------------------
// Main kernel: grid=512 (one patch each), block=256 (4 waves).
// A fragments pinned in registers; B double-buffered in registers so each
// tile's loads are issued one full tile of compute before their first use
// (true prefetch -> counted vmcnt, L2 latency hidden).
// ---------------------------------------------------------------------------
__global__ __launch_bounds__(256, 2) void cpl_main(
    const ushort* __restrict__ Apk, const float* __restrict__ posDot,
    const ushort* __restrict__ bankN, const ushort* __restrict__ bankP,
    const int* __restrict__ flags, float* __restrict__ blockSums)
{
  __shared__ float posNeg[64];
  __shared__ float swS[4][64];

  const int p = blockIdx.x;
  const int t = threadIdx.x;
  if (t < 64) posNeg[t] = -posDot[p * 64 + t] * SCALE;
  __syncthreads();

  const int l = t & 63, w = t >> 6;
  const int r16 = l & 15, kg = l >> 4;

  // ---- A fragments: lane l holds A[mt*16+(l&15)][ks*32+(l>>4)*8 + 0..7] ----
  const ushort* Ab = Apk + (size_t)p * 16384;
  bf16x8 afrag[4][8];
#pragma unroll
  for (int mt = 0; mt < 4; ++mt)
#pragma unroll
    for (int ks = 0; ks < 8; ++ks)
      afrag[mt][ks] = *(const bf16x8*)(Ab + (mt * 16 + r16) * 256 + ks * 32 + kg * 8);
#pragma unroll
  for (int mt = 0; mt < 4; ++mt)
#pragma unroll
    for (int ks = 0; ks < 8; ++ks)
      asm volatile("" : "+v"(afrag[mt][ks]));

  const ushort* bank = (flags[p] ? bankP : bankN);
  // wave w covers columns [w*512,(w+1)*512); lane covers col w*512 + nt*16 + r16
  const ushort* bptr0 = bank + (size_t)(w * 512 + r16) * 256 + kg * 8;

  float s[16];
#pragma unroll
  for (int e = 0; e < 16; ++e) s[e] = 0.f;

  bf16x8 bfA[8], bfB[8];
  f32x4 acc[4];

#define LOADB(BF, NT) do { const ushort* bp_ = bptr0 + (size_t)(NT) * 4096;        \
    _Pragma("unroll") for (int ks = 0; ks < 8; ++ks)                               \
      BF[ks] = *(const bf16x8*)(bp_ + ks * 32); } while (0)

#define MFMA_TILE(BF) do {                                                         \
    _Pragma("unroll") for (int mt = 0; mt < 4; ++mt)                               \
      acc[mt] = *(const f32x4*)&posNeg[mt * 16 + kg * 4];                          \
    _Pragma("unroll") for (int ks = 0; ks < 8; ++ks)                               \
      _Pragma("unroll") for (int mt = 0; mt < 4; ++mt)                             \
        acc[mt] = __builtin_amdgcn_mfma_f32_16x16x32_bf16(afrag[mt][ks], BF[ks],   \
                                                          acc[mt], 0, 0, 0);       \
  } while (0)

#define EXPACC() do {                                                              \
    _Pragma("unroll") for (int mt = 0; mt < 4; ++mt)                               \
      _Pragma("unroll") for (int i = 0; i < 4; ++i)                                \
        s[mt * 4 + i] += fast_exp2(acc[mt][i]); } while (0)

  LOADB(bfA, 0);
  LOADB(bfB, 1);
  for (int nt = 0; nt < 30; nt += 2) {
    MFMA_TILE(bfA);          // waits only on bfA (issued one iteration ago)
    LOADB(bfA, nt + 2);      // prefetch; issues while MFMA/exp2 run
    EXPACC();
    MFMA_TILE(bfB);
    LOADB(bfB, nt + 3);      // nt+3 <= 31
    EXPACC();
  }
  MFMA_TILE(bfA);            // tile 30
  EXPACC();
  MFMA_TILE(bfB);            // tile 31
  EXPACC();

#undef LOADB
#undef MFMA_TILE
#undef EXPACC

  // ---- sum the 16 column-partials (lanes differing in low 4 bits) ----
#pragma unroll
  for (int d = 1; d < 16; d <<= 1)
#pragma unroll
    for (int e = 0; e < 16; ++e) s[e] += __shfl_xor(s[e], d, 64);
  if (r16 == 0) {
#pragma unroll
    for (int mt = 0; mt < 4; ++mt)
#pragma unroll
      for (int i = 0; i < 4; ++i)
        swS[w][mt * 16 + kg * 4 + i] = s[mt * 4 + i];
  }
  __syncthreads();

  // ---- final per-row loss + block reduce (wave 0 only) ----
  if (t < 64) {
    const float S = 1.f + swS[0][t] + swS[1][t] + swS[2][t] + swS[3][t];
    float loss = -logf(1.f / S + EPSV);
#pragma unroll
    for (int d = 1; d < 64; d <<= 1) loss += __shfl_xor(loss, d, 64);
    if (t == 0) blockSums[p] = loss;
  }
}

// ---------------------------------------------------------------------------
// Final: mean of 512 block sums / (512*64).  grid=1, block=256.
// ---------------------------------------------------------------------------
__global__ void cpl_final(const float* __restrict__ blockSums, float* __restrict__ out) {
  const int t = threadIdx.x;
  float s = blockSums[t] + blockSums[t + 256];
#pragma unroll
  for (int d = 1; d < 64; d <<= 1) s += __shfl_xor(s, d, 64);
  __shared__ float ps[4];
  if ((t & 63) == 0) ps[t >> 6] = s;
  __syncthreads();
  if (t == 0) out[0] = (ps[0] + ps[1] + ps[2] + ps[3]) * (1.f / 32768.f);
}

extern "C" void kernel_launch(void* const* d_in, const int* in_sizes, int n_in,
                              void* d_out, int out_size, void* d_ws, size_t ws_size,
                              hipStream_t stream) {
  const float* mainO = (const float*)d_in[0];
  const float* emaO  = (const float*)d_in[1];
  const float* label = (const float*)d_in[2];
  const float* negB  = (const float*)d_in[3];
  const float* posB  = (const float*)d_in[4];
  float* out = (float*)d_out;

  char* ws = (char*)d_ws;
  float*  blockSums = (float*)ws;                        // 2 KiB
  int*    flags     = (int*)(ws + 2048);                 // 2 KiB
  ushort* bankN     = (ushort*)(ws + 4096);              // 1 MiB
  ushort* bankP     = (ushort*)(ws + 4096 + 1048576);    // 1 MiB
  float*  posDot    = (float*)(ws + 4096 + 2097152);     // 128 KiB
  ushort* Apk       = (ushort*)(ws + 4096 + 2097152 + 131072);  // 16.78 MiB

  hipLaunchKernelGGL(cpl_prep, dim3(1088), dim3(256), 0, stream,
                     mainO, emaO, label, negB, posB, Apk, posDot, flags, bankN, bankP);
  hipLaunchKernelGGL(cpl_main, dim3(512), dim3(256), 0, stream,
                     Apk, posDot, bankN, bankP, flags, blockSums);
  hipLaunchKernelGGL(cpl_final, dim3(1), dim3(256), 0, stream, blockSums, out);
}

// Round 6
// 62.982 us; speedup vs baseline: 1.4304x; 1.4304x over previous
//
#include <hip/hip_runtime.h>

typedef __attribute__((ext_vector_type(8))) short bf16x8;
typedef __attribute__((ext_vector_type(4))) float f32x4;

#define EPSV 1e-5f
// (1/TEMP) * log2(e),  TEMP = 0.5  -> exp2-domain scale
#define SCALE 2.885390081777927f

// Must be the builtin — raw inline-asm v_exp_f32 lacks the TRANS-pipe hazard
// nop (asm is opaque to the hazard recognizer) and returns garbage (R4).
__device__ __forceinline__ float fast_exp2(float x) { return __builtin_amdgcn_exp2f(x); }

// async global->LDS DMA, 16 B per lane; LDS dest = uniform base + lane*16.
__device__ __forceinline__ void dma16(const void* g, void* l) {
  __builtin_amdgcn_global_load_lds(
      (const __attribute__((address_space(1))) unsigned*)g,
      (__attribute__((address_space(3))) unsigned*)l, 16, 0, 0);
}

__device__ __forceinline__ ushort f32_to_bf16(float f) {
  union { float f; unsigned u; } cv; cv.f = f;
  unsigned u = cv.u;
  u += 0x7FFFu + ((u >> 16) & 1u);   // round-to-nearest-even
  return (ushort)(u >> 16);
}

// ---------------------------------------------------------------------------
// Fused prep kernel, grid = 512 + 512 + 64 = 1088 blocks, 256 threads.
//  [0,512):   pack anchors  [B,C,H,W] f32 -> Apk[p][n][c] bf16 (coalesced via
//             LDS transpose) + pos-pair dot posDot[p*64+n] (f32)
//  [512,1024): per-patch label mean -> flags
//  [1024,1088): bank repack [L,C,8,8] f32 -> [2048][256] bf16, pre-scaled
// ---------------------------------------------------------------------------
__global__ __launch_bounds__(256) void cpl_prep(
    const float* __restrict__ mainO, const float* __restrict__ emaO,
    const float* __restrict__ label, const float* __restrict__ negB,
    const float* __restrict__ posB,
    ushort* __restrict__ Apk, float* __restrict__ posDot,
    int* __restrict__ flags, ushort* __restrict__ bankN, ushort* __restrict__ bankP)
{
  __shared__ ushort shU[64 * 256];   // 32 KiB
  __shared__ float  shF[4][64];
  const int bid = blockIdx.x;
  const int t = threadIdx.x;

  if (bid < 512) {
    // ---- anchor pack + pos dot: block = (b, y) ----
    const int b = bid >> 6, y = bid & 63;
    const int cg = t >> 4;            // c-offset 0..15
    const int x4 = t & 15;            // float4 index along W
    const float* mB = mainO + (((size_t)b * 256 + cg) * 64 + y) * 64 + x4 * 4;
    const float* eB = emaO  + (((size_t)b * 256 + cg) * 64 + y) * 64 + x4 * 4;
    float4 acc4 = make_float4(0.f, 0.f, 0.f, 0.f);
#pragma unroll
    for (int pass = 0; pass < 16; ++pass) {
      const int c = pass * 16 + cg;
      const float4 mv = *(const float4*)(mB + (size_t)pass * 16 * 4096);
      const float4 ev = *(const float4*)(eB + (size_t)pass * 16 * 4096);
      acc4.x += mv.x * ev.x; acc4.y += mv.y * ev.y;
      acc4.z += mv.z * ev.z; acc4.w += mv.w * ev.w;
      const float vals[4] = {mv.x, mv.y, mv.z, mv.w};
#pragma unroll
      for (int j = 0; j < 4; ++j) {
        const int x = x4 * 4 + j;
        shU[x * 256 + (c ^ ((x & 7) << 3))] = f32_to_bf16(vals[j]);
      }
    }
    // reduce pos partials over c-groups (cg bit0 = lane bit4, bit1 = lane bit5)
    acc4.x += __shfl_xor(acc4.x, 16, 64); acc4.y += __shfl_xor(acc4.y, 16, 64);
    acc4.z += __shfl_xor(acc4.z, 16, 64); acc4.w += __shfl_xor(acc4.w, 16, 64);
    acc4.x += __shfl_xor(acc4.x, 32, 64); acc4.y += __shfl_xor(acc4.y, 32, 64);
    acc4.z += __shfl_xor(acc4.z, 32, 64); acc4.w += __shfl_xor(acc4.w, 32, 64);
    if ((t & 63) < 16) *(float4*)&shF[t >> 6][(t & 15) * 4] = acc4;
    __syncthreads();
    // write packed anchors (coalesced b128)
#pragma unroll
    for (int it = 0; it < 8; ++it) {
      const int lin = it * 256 + t;          // 0..2047
      const int x = lin >> 5, c8 = lin & 31;
      const uint4 v = *(const uint4*)&shU[x * 256 + ((c8 * 8) ^ ((x & 7) << 3))];
      const int p = b * 64 + ((y >> 3) << 3) + (x >> 3);
      const int n = ((y & 7) << 3) + (x & 7);
      *(uint4*)&Apk[((size_t)p * 64 + n) * 256 + c8 * 8] = v;
    }
    if (t < 64) {
      const float pv = shF[0][t] + shF[1][t] + shF[2][t] + shF[3][t];
      const int p = b * 64 + ((y >> 3) << 3) + (t >> 3);
      const int n = ((y & 7) << 3) + (t & 7);
      posDot[p * 64 + n] = pv;
    }
  } else if (bid < 1024) {
    // ---- label mean -> flag ----
    const int p = bid - 512;
    const int b = p >> 6, pj = (p >> 3) & 7, pk = p & 7;
    const size_t base = ((size_t)b * 256 + pj * 32) * 256 + pk * 32;
    float s = 0.f;
#pragma unroll
    for (int i = 0; i < 4; ++i) {
      const int e = t * 4 + i;               // 0..1023, r=e>>5, cc=e&31
      s += label[base + (size_t)(e >> 5) * 256 + (e & 31)];
    }
#pragma unroll
    for (int d = 1; d < 64; d <<= 1) s += __shfl_xor(s, d, 64);
    if ((t & 63) == 0) shF[0][t >> 6] = s;
    __syncthreads();
    if (t == 0)
      flags[p] = ((shF[0][0] + shF[0][1] + shF[0][2] + shF[0][3]) * (1.f / 1024.f) < 0.1f) ? 1 : 0;
  } else {
    // ---- bank repack (pre-scaled by SCALE) ----
    const int bb = bid - 1024;
    const float* src = (bb < 32 ? negB : posB) + (size_t)(bb & 31) * 16384;
    ushort* dst = (bb < 32 ? bankN : bankP) + (size_t)(bb & 31) * 64 * 256;
#pragma unroll 8
    for (int it = 0; it < 64; ++it) {
      const int lin = it * 256 + t;          // [c][posi] linear, coalesced read
      const int c = lin >> 6, posi = lin & 63;
      shU[(posi * 256 + c) ^ ((posi & 31) << 1)] = f32_to_bf16(src[lin] * SCALE);
    }
    __syncthreads();
    unsigned* dst32 = (unsigned*)dst;
#pragma unroll 8
    for (int it = 0; it < 32; ++it) {
      const int lin = it * 256 + t;          // uint index: 128 uints per row
      const int posi = lin >> 7, c = (lin & 127) << 1;
      const int idx = (posi * 256 + c) ^ ((posi & 31) << 1);
      dst32[lin] = *(const unsigned*)&shU[idx];
    }
  }
}

// ---------------------------------------------------------------------------
// Main kernel: grid=512 (one patch each), block=256 (4 waves).
// A fragments pinned in registers. B staged into PER-WAVE-PRIVATE LDS double
// buffers via global_load_lds (zero VGPR cost), counted s_waitcnt vmcnt(8)
// (never 0 in the loop), no __syncthreads in the loop.
// LDS layout per 8KB buffer: byte d = ks*1024 + r16*64 + kg*16  holds bank
// byte  col(r16)*512 + ks*64 + kg*16  -> each ds_read_b128 stripe is 1024
// contiguous bytes (conflict-free), fragment reads = base + ks*1024 imm.
// ---------------------------------------------------------------------------
__global__ __launch_bounds__(256, 2) void cpl_main(
    const ushort* __restrict__ Apk, const float* __restrict__ posDot,
    const ushort* __restrict__ bankN, const ushort* __restrict__ bankP,
    const int* __restrict__ flags, float* __restrict__ blockSums)
{
  __shared__ __align__(1024) char Bsm[4 * 2 * 8192];   // 64 KiB: wave-private dbuf
  __shared__ float posNeg[64];
  __shared__ float swS[4][64];

  const int p = blockIdx.x;
  const int t = threadIdx.x;
  const int l = t & 63, w = t >> 6;
  const int r16 = l & 15, kg = l >> 4;

  if (t < 64) posNeg[t] = -posDot[p * 64 + t] * SCALE;

  const char* bankB = (const char*)(flags[p] ? bankP : bankN);
  // lane-constant part of the DMA source offset (within a tile region)
  const int lv = (l >> 2) * 512 + (l & 3) * 16;
  char* wlds = Bsm + w * 16384;

#define ISSUE(BUF, NT) do {                                                        \
    const char* g0_ = bankB + ((size_t)(w * 512 + (NT) * 16)) * 512 + lv;          \
    char* l0_ = wlds + (BUF) * 8192;                                               \
    _Pragma("unroll") for (int i = 0; i < 8; ++i)                                  \
      dma16(g0_ + i * 64, l0_ + i * 1024);                                         \
  } while (0)

  // prefetch tiles 0 and 1 (16 DMAs outstanding)
  ISSUE(0, 0);
  ISSUE(1, 1);

  __syncthreads();   // posNeg ready (also drains prologue vmcnt once; harmless)

  // ---- A fragments: lane l holds A[mt*16+(l&15)][ks*32+(l>>4)*8 + 0..7] ----
  const ushort* Ab = Apk + (size_t)p * 16384;
  bf16x8 afrag[4][8];
#pragma unroll
  for (int mt = 0; mt < 4; ++mt)
#pragma unroll
    for (int ks = 0; ks < 8; ++ks)
      afrag[mt][ks] = *(const bf16x8*)(Ab + (mt * 16 + r16) * 256 + ks * 32 + kg * 8);
#pragma unroll
  for (int mt = 0; mt < 4; ++mt)
#pragma unroll
    for (int ks = 0; ks < 8; ++ks)
      asm volatile("" : "+v"(afrag[mt][ks]));

  float s[16];
#pragma unroll
  for (int e = 0; e < 16; ++e) s[e] = 0.f;

  f32x4 acc[4];
  const char* rbase = wlds + r16 * 64 + kg * 16;

#define WAITV8() do { asm volatile("s_waitcnt vmcnt(8)" ::: "memory");             \
                      __builtin_amdgcn_sched_barrier(0); } while (0)
#define WAITV0() do { asm volatile("s_waitcnt vmcnt(0)" ::: "memory");             \
                      __builtin_amdgcn_sched_barrier(0); } while (0)

#define MFMA_TILE(BUF) do {                                                        \
    const char* rb_ = rbase + (BUF) * 8192;                                        \
    bf16x8 bfrag[8];                                                               \
    _Pragma("unroll") for (int ks = 0; ks < 8; ++ks)                               \
      bfrag[ks] = *(const bf16x8*)(rb_ + ks * 1024);                               \
    _Pragma("unroll") for (int mt = 0; mt < 4; ++mt)                               \
      acc[mt] = *(const f32x4*)&posNeg[mt * 16 + kg * 4];                          \
    _Pragma("unroll") for (int ks = 0; ks < 8; ++ks)                               \
      _Pragma("unroll") for (int mt = 0; mt < 4; ++mt)                             \
        acc[mt] = __builtin_amdgcn_mfma_f32_16x16x32_bf16(afrag[mt][ks],           \
                      bfrag[ks], acc[mt], 0, 0, 0);                                \
  } while (0)

#define EXPACC() do {                                                              \
    _Pragma("unroll") for (int mt = 0; mt < 4; ++mt)                               \
      _Pragma("unroll") for (int i = 0; i < 4; ++i)                                \
        s[mt * 4 + i] += fast_exp2(acc[mt][i]); } while (0)

#pragma unroll 2
  for (int nt = 0; nt < 30; ++nt) {
    WAITV8();                 // tile nt's 8 DMAs (older than newest 8) are done
    MFMA_TILE(nt & 1);
    __builtin_amdgcn_sched_barrier(0);   // ds_reads consumed before overwrite
    ISSUE(nt & 1, nt + 2);    // refill just-consumed buffer
    EXPACC();
  }
  WAITV8();                   // tile 30 (newest 8 = tile 31's DMAs)
  MFMA_TILE(0);
  EXPACC();
  WAITV0();                   // tile 31
  MFMA_TILE(1);
  EXPACC();

#undef ISSUE
#undef WAITV8
#undef WAITV0
#undef MFMA_TILE
#undef EXPACC

  // ---- sum the 16 column-partials (lanes differing in low 4 bits) ----
#pragma unroll
  for (int d = 1; d < 16; d <<= 1)
#pragma unroll
    for (int e = 0; e < 16; ++e) s[e] += __shfl_xor(s[e], d, 64);
  if (r16 == 0) {
#pragma unroll
    for (int mt = 0; mt < 4; ++mt)
#pragma unroll
      for (int i = 0; i < 4; ++i)
        swS[w][mt * 16 + kg * 4 + i] = s[mt * 4 + i];
  }
  __syncthreads();

  // ---- final per-row loss + block reduce (wave 0 only) ----
  if (t < 64) {
    const float S = 1.f + swS[0][t] + swS[1][t] + swS[2][t] + swS[3][t];
    float loss = -logf(1.f / S + EPSV);
#pragma unroll
    for (int d = 1; d < 64; d <<= 1) loss += __shfl_xor(loss, d, 64);
    if (t == 0) blockSums[p] = loss;
  }
}

// ---------------------------------------------------------------------------
// Final: mean of 512 block sums / (512*64).  grid=1, block=256.
// ---------------------------------------------------------------------------
__global__ void cpl_final(const float* __restrict__ blockSums, float* __restrict__ out) {
  const int t = threadIdx.x;
  float s = blockSums[t] + blockSums[t + 256];
#pragma unroll
  for (int d = 1; d < 64; d <<= 1) s += __shfl_xor(s, d, 64);
  __shared__ float ps[4];
  if ((t & 63) == 0) ps[t >> 6] = s;
  __syncthreads();
  if (t == 0) out[0] = (ps[0] + ps[1] + ps[2] + ps[3]) * (1.f / 32768.f);
}

extern "C" void kernel_launch(void* const* d_in, const int* in_sizes, int n_in,
                              void* d_out, int out_size, void* d_ws, size_t ws_size,
                              hipStream_t stream) {
  const float* mainO = (const float*)d_in[0];
  const float* emaO  = (const float*)d_in[1];
  const float* label = (const float*)d_in[2];
  const float* negB  = (const float*)d_in[3];
  const float* posB  = (const float*)d_in[4];
  float* out = (float*)d_out;

  char* ws = (char*)d_ws;
  float*  blockSums = (float*)ws;                        // 2 KiB
  int*    flags     = (int*)(ws + 2048);                 // 2 KiB
  ushort* bankN     = (ushort*)(ws + 4096);              // 1 MiB
  ushort* bankP     = (ushort*)(ws + 4096 + 1048576);    // 1 MiB
  float*  posDot    = (float*)(ws + 4096 + 2097152);     // 128 KiB
  ushort* Apk       = (ushort*)(ws + 4096 + 2097152 + 131072);  // 16.78 MiB

  hipLaunchKernelGGL(cpl_prep, dim3(1088), dim3(256), 0, stream,
                     mainO, emaO, label, negB, posB, Apk, posDot, flags, bankN, bankP);
  hipLaunchKernelGGL(cpl_main, dim3(512), dim3(256), 0, stream,
                     Apk, posDot, bankN, bankP, flags, blockSums);
  hipLaunchKernelGGL(cpl_final, dim3(1), dim3(256), 0, stream, blockSums, out);
}